// Round 6
// baseline (226.868 us; speedup 1.0000x reference)
//
#include <hip/hip_runtime.h>
#include <math.h>

#define SEQ 2048
#define NBATCH 2
#define DEMB 1024
#define NH 16
#define HD 64
#define NROWS (NBATCH * SEQ) // 4096

typedef __attribute__((ext_vector_type(8))) short short8;   // 8 bf16 (4 VGPR)
typedef __attribute__((ext_vector_type(4))) float f32x4;    // MFMA acc

__device__ __forceinline__ unsigned short f2bf(float f) {
    unsigned int u = __float_as_uint(f);
    u = (u + 0x7FFFu + ((u >> 16) & 1u)) >> 16;   // RNE
    return (unsigned short)u;
}
__device__ __forceinline__ unsigned short f2bf_fast(float f) {
    return (unsigned short)((__float_as_uint(f) + 0x8000u) >> 16); // round-half-up
}

// ============================================================================
// Cast fp32 inputs to bf16. Wq pre-scaled by 0.125*log2(e) (exp2-domain
// softmax downstream).
// ============================================================================
__global__ __launch_bounds__(256) void cast_bf16(
    const float* __restrict__ x, const float* __restrict__ wq,
    const float* __restrict__ wk, const float* __restrict__ wv,
    const float* __restrict__ wo,
    unsigned short* __restrict__ Xb, unsigned short* __restrict__ Wb,
    unsigned short* __restrict__ Wob)
{
    const int q = blockIdx.x * 256 + threadIdx.x; // quad index
    float4 v; unsigned short* dst; float sc = 1.f;
    if (q < 1048576) {                       // X: 4194304 elems
        v = ((const float4*)x)[q];
        dst = Xb + q * 4;
    } else if (q < 1835008) {                // Wq|Wk|Wv concat: 3145728 elems
        const int e = (q - 1048576) * 4;
        const int which = e >> 20;
        const int off = e & 1048575;
        const float* s = (which == 0) ? wq : (which == 1) ? wk : wv;
        v = *(const float4*)&s[off];
        sc = (which == 0) ? 0.18033688011112042f : 1.f;  // 0.125*log2(e)
        dst = Wb + e;
    } else {                                 // Wo: 1048576 elems
        const int j = q - 1835008;
        v = ((const float4*)wo)[j];
        dst = Wob + j * 4;
    }
    ushort4 o;
    o.x = f2bf(v.x * sc); o.y = f2bf(v.y * sc);
    o.z = f2bf(v.z * sc); o.w = f2bf(v.w * sc);
    *(ushort4*)dst = o;
}

// ============================================================================
// bf16 MFMA NT-GEMM (R2-proven structure): 128x128 tile, BK=32, 4 waves,
// reg-staged LDS with next-tile register prefetch overlapping MFMA.
// A=Xb[4096][1024], B=Wb[3072][1024]. Q,K,V written bf16 [b,h,s,d].
// ============================================================================
__global__ __launch_bounds__(256) void gemm_qkv(
    const unsigned short* __restrict__ Xb, const unsigned short* __restrict__ Wb,
    unsigned short* __restrict__ Qb, unsigned short* __restrict__ Kb,
    unsigned short* __restrict__ Vb)
{
    __shared__ __align__(16) short As[128 * 32];
    __shared__ __align__(16) short Bs[128 * 32];

    const int tid = threadIdx.x;
    const int m0 = blockIdx.y * 128, n0 = blockIdx.x * 128;

    const int sr = tid >> 2, sg = tid & 3;
    const int slot = sg ^ ((sr >> 1) & 3);        // 2-way-free XOR swizzle
    const int st0 = sr * 32 + slot * 8;
    const int st1 = (sr + 64) * 32 + slot * 8;

    const int lane = tid & 63, w = tid >> 6;
    const int wr = w >> 1, wc = w & 1;
    const int fr = lane & 15, fq = lane >> 4;

    int offA[4], offB[4];
#pragma unroll
    for (int m = 0; m < 4; ++m) {
        const int rA = wr * 64 + m * 16 + fr;
        offA[m] = rA * 32 + ((fq ^ ((rA >> 1) & 3)) * 8);
        const int rB = wc * 64 + m * 16 + fr;
        offB[m] = rB * 32 + ((fq ^ ((rB >> 1) & 3)) * 8);
    }

    f32x4 acc[4][4];
#pragma unroll
    for (int m = 0; m < 4; ++m)
#pragma unroll
        for (int n = 0; n < 4; ++n) acc[m][n] = (f32x4){0.f, 0.f, 0.f, 0.f};

    const unsigned short* ga0 = Xb + (m0 + sr) * 1024 + sg * 8;
    const unsigned short* ga1 = Xb + (m0 + 64 + sr) * 1024 + sg * 8;
    const unsigned short* gb0 = Wb + (n0 + sr) * 1024 + sg * 8;
    const unsigned short* gb1 = Wb + (n0 + 64 + sr) * 1024 + sg * 8;

    short8 ra0 = *(const short8*)ga0, ra1 = *(const short8*)ga1;
    short8 rb0 = *(const short8*)gb0, rb1 = *(const short8*)gb1;

    for (int k = 0; k < 32; ++k) {
        __syncthreads();
        *(short8*)&As[st0] = ra0; *(short8*)&As[st1] = ra1;
        *(short8*)&Bs[st0] = rb0; *(short8*)&Bs[st1] = rb1;
        __syncthreads();
        if (k < 31) {
            ga0 += 32; ga1 += 32; gb0 += 32; gb1 += 32;
            ra0 = *(const short8*)ga0; ra1 = *(const short8*)ga1;
            rb0 = *(const short8*)gb0; rb1 = *(const short8*)gb1;
        }
        short8 af[4], bg[4];
#pragma unroll
        for (int m = 0; m < 4; ++m) af[m] = *(const short8*)&As[offA[m]];
#pragma unroll
        for (int n = 0; n < 4; ++n) bg[n] = *(const short8*)&Bs[offB[n]];
#pragma unroll
        for (int m = 0; m < 4; ++m)
#pragma unroll
            for (int n = 0; n < 4; ++n)
                acc[m][n] = __builtin_amdgcn_mfma_f32_16x16x32_bf16(
                    af[m], bg[n], acc[m][n], 0, 0, 0);
    }

#pragma unroll
    for (int n = 0; n < 4; ++n) {
        const int col = n0 + wc * 64 + n * 16 + fr;
        const int which = col >> 10;
        const int h = (col >> 6) & 15;
        const int d = col & 63;
        unsigned short* Out = (which == 0) ? Qb : (which == 1) ? Kb : Vb;
#pragma unroll
        for (int m = 0; m < 4; ++m) {
            const int rowb = m0 + wr * 64 + m * 16 + fq * 4;
#pragma unroll
            for (int r = 0; r < 4; ++r) {
                const int row = rowb + r;
                const int b = row >> 11, s = row & 2047;
                Out[(((size_t)b * NH + h) * SEQ + s) * HD + d] =
                    f2bf(acc[m][n][r]);
            }
        }
    }
}

// ============================================================================
// V [b,h,s,d] -> Vt [b,h,d,s] via LDS tile.
// ============================================================================
__global__ __launch_bounds__(256) void transpose_v(
    const unsigned short* __restrict__ Vb, unsigned short* __restrict__ Vtb)
{
    __shared__ short T[64][72];
    const int s0tile = blockIdx.x * 64;
    const size_t bh = blockIdx.y;
    const unsigned short* src = Vb + bh * SEQ * HD;
    unsigned short* dst = Vtb + bh * (size_t)HD * SEQ;
    const int t = threadIdx.x;
    const int sr = t >> 3, sc = t & 7;

    const short8 a = *(const short8*)&src[(size_t)(s0tile + sr) * HD + sc * 8];
    const short8 bb = *(const short8*)&src[(size_t)(s0tile + sr + 32) * HD + sc * 8];
    *(short8*)&T[sr][sc * 8] = a;
    *(short8*)&T[sr + 32][sc * 8] = bb;
    __syncthreads();

    const int d = t >> 2, s0 = (t & 3) * 16;
    short8 o0, o1;
#pragma unroll
    for (int i = 0; i < 8; ++i) {
        o0[i] = T[s0 + i][d];
        o1[i] = T[s0 + 8 + i][d];
    }
    *(short8*)&dst[(size_t)d * SEQ + s0tile + s0] = o0;
    *(short8*)&dst[(size_t)d * SEQ + s0tile + s0 + 8] = o1;
}

// ============================================================================
// MFMA flash attention v4: kv-split-2 for occupancy.
// 512 blocks x 8 waves. Waves (u, kvhalf): u in 0..3 selects a 32-row Q unit
// (paired for balance: {2pq, 63-2pq, 2pq+1, 62-2pq}), kvhalf splits that
// unit's kv-tile range [0,T) into [0,Th) / [Th,T). 4096 waves total ->
// 4 waves/SIMD (2x R5). Direct-global K/V fragment loads, no per-tile
// barriers. End-of-block combine: upper waves dump (m,l,O-f32) into the
// then-dead P buffer; lower waves merge, normalize, write ctx.
// ============================================================================
__global__ __launch_bounds__(512, 2) void flash_mfma4(
    const unsigned short* __restrict__ Qb, const unsigned short* __restrict__ Kb,
    const unsigned short* __restrict__ Vtb, unsigned short* __restrict__ ctx)
{
    __shared__ __align__(16) short Ps[8 * 2048];  // per-wave P [32 q][64 kv] bf16; reused as f32 O-overlay
    __shared__ float ML[4][2][32];                // [u][m|l][row]

    const int pq = blockIdx.x;   // 0..15
    const int h  = blockIdx.y;
    const int b  = blockIdx.z;
    const size_t bh = (size_t)b * NH + h;
    const unsigned short* __restrict__ Qg = Qb  + bh * SEQ * HD;
    const unsigned short* __restrict__ Kg = Kb  + bh * SEQ * HD;
    const unsigned short* __restrict__ Vg = Vtb + bh * (size_t)HD * SEQ;

    const int tid = threadIdx.x;
    const int lane = tid & 63, w = tid >> 6;
    const int fr = lane & 15, fq = lane >> 4;
    const int u = w & 3, kvhalf = w >> 2;

    const int unit = (u == 0) ? 2 * pq : (u == 1) ? 63 - 2 * pq
                   : (u == 2) ? 2 * pq + 1 : 62 - 2 * pq;   // 0..63
    const int qbase = unit * 32;
    const int T  = (unit >> 1) + 1;        // kv tiles for these rows
    const int Th = (T + 1) >> 1;
    const int j0 = kvhalf ? Th : 0;
    const int j1 = kvhalf ? T : Th;

    // Q fragments (MFMA B-operand of the swapped QK^T)
    short8 qa[2][2];
#pragma unroll
    for (int m = 0; m < 2; ++m)
#pragma unroll
        for (int ks = 0; ks < 2; ++ks)
            qa[m][ks] = *(const short8*)&Qg[(size_t)(qbase + m * 16 + fr) * HD + ks * 32 + fq * 8];

    f32x4 o[2][4];
    float mold[2], lsum[2];
#pragma unroll
    for (int m = 0; m < 2; ++m) {
        mold[m] = -3e38f; lsum[m] = 0.f;
#pragma unroll
        for (int n = 0; n < 4; ++n) o[m][n] = (f32x4){0.f, 0.f, 0.f, 0.f};
    }

    short* const Pw = Ps + w * 2048;
    const int swz = (fr & 7) << 3;

    for (int j = j0; j < j1; ++j) {
        const int kvb = j * 64;

        // ---- direct global fragment loads (K needed first; V ~600cyc later)
        short8 kf[2][4], vf[2][4];
#pragma unroll
        for (int ks = 0; ks < 2; ++ks)
#pragma unroll
            for (int n = 0; n < 4; ++n)
                kf[ks][n] = *(const short8*)&Kg[(size_t)(kvb + n * 16 + fr) * HD + ks * 32 + fq * 8];
#pragma unroll
        for (int ks = 0; ks < 2; ++ks)
#pragma unroll
            for (int n = 0; n < 4; ++n)
                vf[ks][n] = *(const short8*)&Vg[(size_t)(n * 16 + fr) * SEQ + kvb + ks * 32 + fq * 8];

        // ---- S^T = K Q^T : lane holds q-col = m*16+fr ----
        f32x4 st[4][2];
#pragma unroll
        for (int n = 0; n < 4; ++n)
#pragma unroll
            for (int m = 0; m < 2; ++m) st[n][m] = (f32x4){0.f, 0.f, 0.f, 0.f};
#pragma unroll
        for (int ks = 0; ks < 2; ++ks) {
            __builtin_amdgcn_s_setprio(1);
#pragma unroll
            for (int n = 0; n < 4; ++n)
#pragma unroll
                for (int m = 0; m < 2; ++m)
                    st[n][m] = __builtin_amdgcn_mfma_f32_16x16x32_bf16(
                        kf[ks][n], qa[m][ks], st[n][m], 0, 0, 0);
            __builtin_amdgcn_s_setprio(0);
        }

        // ---- causal mask (kv = kvb+n*16+fq*4+r, q = qbase+m*16+fr) ----
        if (kvb + 63 > qbase) {
#pragma unroll
            for (int n = 0; n < 4; ++n) {
                const int kv = kvb + n * 16 + fq * 4;
#pragma unroll
                for (int m = 0; m < 2; ++m) {
                    const int q = qbase + m * 16 + fr;
#pragma unroll
                    for (int r = 0; r < 4; ++r)
                        if (kv + r > q) st[n][m][r] = -3e38f;
                }
            }
        }

        // ---- row max (in-lane + 2 shfl across fq partners) ----
        float pmax[2];
#pragma unroll
        for (int m = 0; m < 2; ++m) {
            float t0 = fmaxf(fmaxf(st[0][m][0], st[0][m][1]), fmaxf(st[0][m][2], st[0][m][3]));
            float t1 = fmaxf(fmaxf(st[1][m][0], st[1][m][1]), fmaxf(st[1][m][2], st[1][m][3]));
            float t2 = fmaxf(fmaxf(st[2][m][0], st[2][m][1]), fmaxf(st[2][m][2], st[2][m][3]));
            float t3 = fmaxf(fmaxf(st[3][m][0], st[3][m][1]), fmaxf(st[3][m][2], st[3][m][3]));
            float t = fmaxf(fmaxf(t0, t1), fmaxf(t2, t3));
            t = fmaxf(t, __shfl_xor(t, 16));
            t = fmaxf(t, __shfl_xor(t, 32));
            pmax[m] = t;
        }

        // ---- defer-max (T13): rescale only if max grew > 8 (log2 units) ----
        const float growth = fmaxf(pmax[0] - mold[0], pmax[1] - mold[1]);
        if (!__all(growth <= 8.0f)) {
            float resc[2];
#pragma unroll
            for (int m = 0; m < 2; ++m) {
                const float nm = fmaxf(mold[m], pmax[m]);
                resc[m] = exp2f(mold[m] - nm);
                mold[m] = nm;
                lsum[m] *= resc[m];
            }
#pragma unroll
            for (int m = 0; m < 2; ++m)
#pragma unroll
                for (int rr = 0; rr < 4; ++rr) {
                    const float rsc = __shfl(resc[m], fq * 4 + rr);
#pragma unroll
                    for (int n = 0; n < 4; ++n) o[m][n][rr] *= rsc;
                }
        }

        // ---- exp2, row-sum, packed P -> wave-private LDS ----
#pragma unroll
        for (int m = 0; m < 2; ++m) {
            float rs = 0.f;
            const int prow = m * 16 + fr;
#pragma unroll
            for (int n = 0; n < 4; ++n) {
                const float p0 = exp2f(st[n][m][0] - mold[m]);
                const float p1 = exp2f(st[n][m][1] - mold[m]);
                const float p2 = exp2f(st[n][m][2] - mold[m]);
                const float p3 = exp2f(st[n][m][3] - mold[m]);
                rs += (p0 + p1) + (p2 + p3);
                ushort4 pk;
                pk.x = f2bf_fast(p0); pk.y = f2bf_fast(p1);
                pk.z = f2bf_fast(p2); pk.w = f2bf_fast(p3);
                *(ushort4*)&Pw[prow * 64 + ((n * 16 + fq * 4) ^ swz)] = pk;
            }
            rs += __shfl_xor(rs, 16);
            rs += __shfl_xor(rs, 32);
            lsum[m] += rs;
        }

        // ---- O += P @ Vt (same-wave DS write->read) ----
#pragma unroll
        for (int ks = 0; ks < 2; ++ks) {
            short8 pa[2];
#pragma unroll
            for (int m = 0; m < 2; ++m) {
                const int row = m * 16 + fr;
                pa[m] = *(const short8*)&Pw[row * 64 + ((ks * 32 + fq * 8) ^ swz)];
            }
            __builtin_amdgcn_s_setprio(1);
#pragma unroll
            for (int m = 0; m < 2; ++m)
#pragma unroll
                for (int n = 0; n < 4; ++n)
                    o[m][n] = __builtin_amdgcn_mfma_f32_16x16x32_bf16(
                        pa[m], vf[ks][n], o[m][n], 0, 0, 0);
            __builtin_amdgcn_s_setprio(0);
        }
    }

    // ======== combine the two kv-halves ========
    __syncthreads();   // all P usage done; overlay becomes safe
    float* const Of = (float*)Ps;
    if (kvhalf == 1) {
        // dump partial O (f32) + stats into overlay
#pragma unroll
        for (int m = 0; m < 2; ++m)
#pragma unroll
            for (int n = 0; n < 4; ++n)
#pragma unroll
                for (int r = 0; r < 4; ++r)
                    Of[u * 2048 + (m * 16 + fq * 4 + r) * 64 + n * 16 + fr] = o[m][n][r];
        if (fq == 0) {
#pragma unroll
            for (int m = 0; m < 2; ++m) {
                ML[u][0][m * 16 + fr] = mold[m];
                ML[u][1][m * 16 + fr] = lsum[m];
            }
        }
    }
    __syncthreads();
    if (kvhalf == 0) {
        // merge with partner, normalize, write ctx bf16 [b, s, h*64+d]
#pragma unroll
        for (int m = 0; m < 2; ++m)
#pragma unroll
            for (int rr = 0; rr < 4; ++rr) {
                const int prow = m * 16 + fq * 4 + rr;
                const float m1 = __shfl(mold[m], fq * 4 + rr);
                const float l1 = __shfl(lsum[m], fq * 4 + rr);
                const float m2 = ML[u][0][prow];
                const float l2 = ML[u][1][prow];
                const float mm = fmaxf(m1, m2);
                const float a1 = exp2f(m1 - mm);
                const float a2 = exp2f(m2 - mm);
                const float inv = 1.f / (l1 * a1 + l2 * a2);
                const int q = qbase + prow;
                const size_t rowoff = ((size_t)b * SEQ + q) * DEMB + h * HD;
#pragma unroll
                for (int n = 0; n < 4; ++n) {
                    const float o2 = Of[u * 2048 + prow * 64 + n * 16 + fr];
                    ctx[rowoff + n * 16 + fr] =
                        f2bf((o[m][n][rr] * a1 + o2 * a2) * inv);
                }
            }
    }
}

// ============================================================================
// O-projection (R2-proven structure): ctx_bf16 @ Wob^T + bo -> out fp32.
// ============================================================================
__global__ __launch_bounds__(256) void gemm_out(
    const unsigned short* __restrict__ Cb, const unsigned short* __restrict__ Wob,
    const float* __restrict__ bo, float* __restrict__ Out)
{
    __shared__ __align__(16) short As[128 * 32];
    __shared__ __align__(16) short Bs[128 * 32];

    const int tid = threadIdx.x;
    const int m0 = blockIdx.y * 128, n0 = blockIdx.x * 128;
    const int sr = tid >> 2, sg = tid & 3;
    const int slot = sg ^ ((sr >> 1) & 3);
    const int st0 = sr * 32 + slot * 8;
    const int st1 = (sr + 64) * 32 + slot * 8;

    const int lane = tid & 63, w = tid >> 6;
    const int wr = w >> 1, wc = w & 1;
    const int fr = lane & 15, fq = lane >> 4;

    int offA[4], offB[4];
#pragma unroll
    for (int m = 0; m < 4; ++m) {
        const int rA = wr * 64 + m * 16 + fr;
        offA[m] = rA * 32 + ((fq ^ ((rA >> 1) & 3)) * 8);
        const int rB = wc * 64 + m * 16 + fr;
        offB[m] = rB * 32 + ((fq ^ ((rB >> 1) & 3)) * 8);
    }

    f32x4 acc[4][4];
#pragma unroll
    for (int m = 0; m < 4; ++m)
#pragma unroll
        for (int n = 0; n < 4; ++n) acc[m][n] = (f32x4){0.f, 0.f, 0.f, 0.f};

    const unsigned short* ga0 = Cb + (m0 + sr) * 1024 + sg * 8;
    const unsigned short* ga1 = Cb + (m0 + 64 + sr) * 1024 + sg * 8;
    const unsigned short* gb0 = Wob + (n0 + sr) * 1024 + sg * 8;
    const unsigned short* gb1 = Wob + (n0 + 64 + sr) * 1024 + sg * 8;

    short8 ra0 = *(const short8*)ga0, ra1 = *(const short8*)ga1;
    short8 rb0 = *(const short8*)gb0, rb1 = *(const short8*)gb1;

    for (int k = 0; k < 32; ++k) {
        __syncthreads();
        *(short8*)&As[st0] = ra0; *(short8*)&As[st1] = ra1;
        *(short8*)&Bs[st0] = rb0; *(short8*)&Bs[st1] = rb1;
        __syncthreads();
        if (k < 31) {
            ga0 += 32; ga1 += 32; gb0 += 32; gb1 += 32;
            ra0 = *(const short8*)ga0; ra1 = *(const short8*)ga1;
            rb0 = *(const short8*)gb0; rb1 = *(const short8*)gb1;
        }
        short8 af[4], bg[4];
#pragma unroll
        for (int m = 0; m < 4; ++m) af[m] = *(const short8*)&As[offA[m]];
#pragma unroll
        for (int n = 0; n < 4; ++n) bg[n] = *(const short8*)&Bs[offB[n]];
#pragma unroll
        for (int m = 0; m < 4; ++m)
#pragma unroll
            for (int n = 0; n < 4; ++n)
                acc[m][n] = __builtin_amdgcn_mfma_f32_16x16x32_bf16(
                    af[m], bg[n], acc[m][n], 0, 0, 0);
    }

#pragma unroll
    for (int n = 0; n < 4; ++n) {
        const int col = n0 + wc * 64 + n * 16 + fr;
        const float bias = bo[col];
#pragma unroll
        for (int m = 0; m < 4; ++m) {
            const int rowb = m0 + wr * 64 + m * 16 + fq * 4;
#pragma unroll
            for (int r = 0; r < 4; ++r)
                Out[(size_t)(rowb + r) * DEMB + col] = acc[m][n][r] + bias;
        }
    }
}

extern "C" void kernel_launch(void* const* d_in, const int* in_sizes, int n_in,
                              void* d_out, int out_size, void* d_ws, size_t ws_size,
                              hipStream_t stream) {
    const float* x  = (const float*)d_in[0];
    const float* Wq = (const float*)d_in[1];
    const float* Wk = (const float*)d_in[2];
    const float* Wv = (const float*)d_in[3];
    const float* Wo = (const float*)d_in[4];
    const float* bo = (const float*)d_in[5];
    float* out = (float*)d_out;

    char* w = (char*)d_ws;
    const size_t MB = 1024 * 1024;
    unsigned short* Qb   = (unsigned short*)(w);            //  8 MB
    unsigned short* Kb   = (unsigned short*)(w + 8  * MB);  //  8 MB
    unsigned short* Vb   = (unsigned short*)(w + 16 * MB);  //  8 MB [b,h,s,d]
    unsigned short* Cb   = (unsigned short*)(w + 24 * MB);  //  8 MB ctx
    unsigned short* Xb   = (unsigned short*)(w + 32 * MB);  //  8 MB (dead after gemm_qkv)
    unsigned short* Wb   = (unsigned short*)(w + 40 * MB);  //  6 MB (q|k|v)
    unsigned short* Wob  = (unsigned short*)(w + 46 * MB);  //  2 MB
    unsigned short* Vtb  = Xb;                              //  reuse: [b,h,d,s]

    cast_bf16<<<8192, 256, 0, stream>>>(x, Wq, Wk, Wv, Wo, Xb, Wb, Wob);
    gemm_qkv<<<dim3(24, 32), 256, 0, stream>>>(Xb, Wb, Qb, Kb, Vb);
    transpose_v<<<dim3(SEQ / 64, NBATCH * NH), 256, 0, stream>>>(Vb, Vtb);
    flash_mfma4<<<dim3(16, NH, NBATCH), 512, 0, stream>>>(Qb, Kb, Vtb, Cb);
    gemm_out<<<dim3(8, 32), 256, 0, stream>>>(Cb, Wob, bo, out);
}

// Round 8
// 215.206 us; speedup vs baseline: 1.0542x; 1.0542x over previous
//
#include <hip/hip_runtime.h>
#include <math.h>

#define SEQ 2048
#define NBATCH 2
#define DEMB 1024
#define NH 16
#define HD 64
#define NROWS (NBATCH * SEQ) // 4096

typedef __attribute__((ext_vector_type(8))) short short8;   // 8 bf16 (4 VGPR)
typedef __attribute__((ext_vector_type(4))) float f32x4;    // MFMA acc

__device__ __forceinline__ unsigned short f2bf(float f) {
    unsigned int u = __float_as_uint(f);
    u = (u + 0x7FFFu + ((u >> 16) & 1u)) >> 16;   // RNE
    return (unsigned short)u;
}
__device__ __forceinline__ unsigned short f2bf_fast(float f) {
    return (unsigned short)((__float_as_uint(f) + 0x8000u) >> 16); // round-half-up
}

// Direct global->LDS DMA, 16B per lane. LDS dest = wave-uniform base + lane*16.
__device__ __forceinline__ void gload_lds16(const void* g, void* l) {
    typedef const __attribute__((address_space(1))) unsigned int* gp_t;
    typedef __attribute__((address_space(3))) unsigned int* lp_t;
    __builtin_amdgcn_global_load_lds((gp_t)g, (lp_t)l, 16, 0, 0);
}

// ============================================================================
// Cast WEIGHTS only to bf16 (X is cast in-flight inside gemm_qkv now).
// Wq pre-scaled by 0.125*log2(e) (exp2-domain softmax downstream).
// ============================================================================
__global__ __launch_bounds__(256) void cast_w(
    const float* __restrict__ wq, const float* __restrict__ wk,
    const float* __restrict__ wv, const float* __restrict__ wo,
    unsigned short* __restrict__ Wb, unsigned short* __restrict__ Wob)
{
    const int q = blockIdx.x * 256 + threadIdx.x; // quad index, 1048576 total
    float4 v; unsigned short* dst; float sc = 1.f;
    if (q < 786432) {                        // Wq|Wk|Wv concat: 3145728 elems
        const int e = q * 4;
        const int which = e >> 20;
        const int off = e & 1048575;
        const float* s = (which == 0) ? wq : (which == 1) ? wk : wv;
        v = *(const float4*)&s[off];
        sc = (which == 0) ? 0.18033688011112042f : 1.f;  // 0.125*log2(e)
        dst = Wb + e;
    } else {                                 // Wo: 1048576 elems
        const int j = q - 786432;
        v = ((const float4*)wo)[j];
        dst = Wob + j * 4;
    }
    ushort4 o;
    o.x = f2bf(v.x * sc); o.y = f2bf(v.y * sc);
    o.z = f2bf(v.z * sc); o.w = f2bf(v.w * sc);
    *(ushort4*)dst = o;
}

// ============================================================================
// QKV GEMM, fused X-cast, 2-phase double-buffered K loop.
// A = X fp32 [4096][1024] reg-staged + converted to bf16 in-flight.
// B = Wb bf16 [3072][1024] via global_load_lds (pre-swizzled source).
// 128x128 tile, BK=32, 4 waves, one barrier per K-step.
// Q,K,V written bf16 [b,h,s,d].
// ============================================================================
__global__ __launch_bounds__(256) void gemm_qkv(
    const float* __restrict__ X, const unsigned short* __restrict__ Wb,
    unsigned short* __restrict__ Qb, unsigned short* __restrict__ Kb,
    unsigned short* __restrict__ Vb)
{
    __shared__ __align__(16) short Asb[2][128 * 32];
    __shared__ __align__(16) short Bsb[2][128 * 32];

    const int tid = threadIdx.x;
    const int m0 = blockIdx.y * 128, n0 = blockIdx.x * 128;
    const int lane = tid & 63, w = tid >> 6;
    const int wr = w >> 1, wc = w & 1;
    const int fr = lane & 15, fq = lane >> 4;

    // ---- A staging geometry (reg path): row sr, 16-col half hf ----
    const int sr = tid >> 1, hf = tid & 1;
    const int sA0 = sr * 32 + (((2 * hf)     ^ ((sr >> 1) & 3)) * 8);
    const int sA1 = sr * 32 + (((2 * hf + 1) ^ ((sr >> 1) & 3)) * 8);
    const float* gAr = X + (size_t)(m0 + sr) * 1024 + hf * 16;

    // ---- B staging geometry (DMA path): pre-swizzled global source ----
    int soffB[2];
#pragma unroll
    for (int i = 0; i < 2; ++i) {
        const int chunk = (w * 2 + i) * 64 + lane;
        const int row = chunk >> 2;
        const int cg = (chunk & 3) ^ ((row >> 1) & 3);
        soffB[i] = row * 1024 + cg * 8;
    }
    const unsigned short* Bbase = Wb + (size_t)n0 * 1024;

    // ---- fragment read offsets (within one 4096-short plane) ----
    int offA[4], offB[4];
#pragma unroll
    for (int m = 0; m < 4; ++m) {
        const int rA = wr * 64 + m * 16 + fr;
        offA[m] = rA * 32 + ((fq ^ ((rA >> 1) & 3)) * 8);
        const int rB = wc * 64 + m * 16 + fr;
        offB[m] = rB * 32 + ((fq ^ ((rB >> 1) & 3)) * 8);
    }

    f32x4 acc[4][4];
#pragma unroll
    for (int m = 0; m < 4; ++m)
#pragma unroll
        for (int n = 0; n < 4; ++n) acc[m][n] = (f32x4){0.f, 0.f, 0.f, 0.f};

    // ---- prologue: stage tile 0 into buffer 0 ----
    {
        const float4 b0 = *(const float4*)&gAr[0];
        const float4 b1 = *(const float4*)&gAr[4];
        const float4 b2 = *(const float4*)&gAr[8];
        const float4 b3 = *(const float4*)&gAr[12];
#pragma unroll
        for (int i = 0; i < 2; ++i)
            gload_lds16(Bbase + soffB[i], &Bsb[0][(w * 2 + i) * 512]);
        short8 p0, p1;
        p0[0] = f2bf(b0.x); p0[1] = f2bf(b0.y); p0[2] = f2bf(b0.z); p0[3] = f2bf(b0.w);
        p0[4] = f2bf(b1.x); p0[5] = f2bf(b1.y); p0[6] = f2bf(b1.z); p0[7] = f2bf(b1.w);
        p1[0] = f2bf(b2.x); p1[1] = f2bf(b2.y); p1[2] = f2bf(b2.z); p1[3] = f2bf(b2.w);
        p1[4] = f2bf(b3.x); p1[5] = f2bf(b3.y); p1[6] = f2bf(b3.z); p1[7] = f2bf(b3.w);
        *(short8*)&Asb[0][sA0] = p0;
        *(short8*)&Asb[0][sA1] = p1;
    }
    __syncthreads();

    int cur = 0;
    for (int t = 0; t < 32; ++t) {
        // ---- issue next-tile staging (overlaps with MFMA below) ----
        float4 b0, b1, b2, b3;
        const int nxt = cur ^ 1;
        if (t < 31) {
            const int k1 = (t + 1) * 32;
            b0 = *(const float4*)&gAr[k1];
            b1 = *(const float4*)&gAr[k1 + 4];
            b2 = *(const float4*)&gAr[k1 + 8];
            b3 = *(const float4*)&gAr[k1 + 12];
#pragma unroll
            for (int i = 0; i < 2; ++i)
                gload_lds16(Bbase + soffB[i] + k1, &Bsb[nxt][(w * 2 + i) * 512]);
        }

        // ---- compute on current buffer ----
        short8 af[4], bg[4];
#pragma unroll
        for (int m = 0; m < 4; ++m) af[m] = *(const short8*)&Asb[cur][offA[m]];
#pragma unroll
        for (int n = 0; n < 4; ++n) bg[n] = *(const short8*)&Bsb[cur][offB[n]];
#pragma unroll
        for (int m = 0; m < 4; ++m)
#pragma unroll
            for (int n = 0; n < 4; ++n)
                acc[m][n] = __builtin_amdgcn_mfma_f32_16x16x32_bf16(
                    af[m], bg[n], acc[m][n], 0, 0, 0);

        // ---- write-late: convert A regs and store to next buffer ----
        if (t < 31) {
            short8 p0, p1;
            p0[0] = f2bf(b0.x); p0[1] = f2bf(b0.y); p0[2] = f2bf(b0.z); p0[3] = f2bf(b0.w);
            p0[4] = f2bf(b1.x); p0[5] = f2bf(b1.y); p0[6] = f2bf(b1.z); p0[7] = f2bf(b1.w);
            p1[0] = f2bf(b2.x); p1[1] = f2bf(b2.y); p1[2] = f2bf(b2.z); p1[3] = f2bf(b2.w);
            p1[4] = f2bf(b3.x); p1[5] = f2bf(b3.y); p1[6] = f2bf(b3.z); p1[7] = f2bf(b3.w);
            *(short8*)&Asb[nxt][sA0] = p0;
            *(short8*)&Asb[nxt][sA1] = p1;
        }
        __syncthreads();   // drains DMA (vm) + A writes (lgkm); next tile ready
        cur = nxt;
    }

    // ---- epilogue: C row=(b,s), col->(which,h,d); write bf16 [b,h,s,d] ----
#pragma unroll
    for (int n = 0; n < 4; ++n) {
        const int col = n0 + wc * 64 + n * 16 + fr;
        const int which = col >> 10;
        const int h = (col >> 6) & 15;
        const int d = col & 63;
        unsigned short* Out = (which == 0) ? Qb : (which == 1) ? Kb : Vb;
#pragma unroll
        for (int m = 0; m < 4; ++m) {
            const int rowb = m0 + wr * 64 + m * 16 + fq * 4;
#pragma unroll
            for (int r = 0; r < 4; ++r) {
                const int row = rowb + r;
                const int b = row >> 11, s = row & 2047;
                Out[(((size_t)b * NH + h) * SEQ + s) * HD + d] =
                    f2bf(acc[m][n][r]);
            }
        }
    }
}

// ============================================================================
// V [b,h,s,d] -> Vt [b,h,d,s] via LDS tile (verbatim R4).
// ============================================================================
__global__ __launch_bounds__(256) void transpose_v(
    const unsigned short* __restrict__ Vb, unsigned short* __restrict__ Vtb)
{
    __shared__ short T[64][72];
    const int s0tile = blockIdx.x * 64;
    const size_t bh = blockIdx.y;
    const unsigned short* src = Vb + bh * SEQ * HD;
    unsigned short* dst = Vtb + bh * (size_t)HD * SEQ;
    const int t = threadIdx.x;
    const int sr = t >> 3, sc = t & 7;

    const short8 a = *(const short8*)&src[(size_t)(s0tile + sr) * HD + sc * 8];
    const short8 bb = *(const short8*)&src[(size_t)(s0tile + sr + 32) * HD + sc * 8];
    *(short8*)&T[sr][sc * 8] = a;
    *(short8*)&T[sr + 32][sc * 8] = bb;
    __syncthreads();

    const int d = t >> 2, s0 = (t & 3) * 16;
    short8 o0, o1;
#pragma unroll
    for (int i = 0; i < 8; ++i) {
        o0[i] = T[s0 + i][d];
        o1[i] = T[s0 + 8 + i][d];
    }
    *(short8*)&dst[(size_t)d * SEQ + s0tile + s0] = o0;
    *(short8*)&dst[(size_t)d * SEQ + s0tile + s0 + 8] = o1;
}

// ============================================================================
// MFMA flash attention (R4 flash_mfma2 — proven 64.4 us).
// 256 blocks x 512 threads. Waves 0-3: qt=bx; waves 4-7: qt=15-bx.
// Shared K/Vt LDS staging (XOR-swizzled); swapped QK^T softmax; defer-max.
// ============================================================================
__global__ __launch_bounds__(512) void flash_mfma2(
    const unsigned short* __restrict__ Qb, const unsigned short* __restrict__ Kb,
    const unsigned short* __restrict__ Vtb, unsigned short* __restrict__ ctx)
{
    __shared__ __align__(16) short Ks[64 * 64];
    __shared__ __align__(16) short Vs[64 * 64];     // Vt tile [d][kv]
    __shared__ __align__(16) short Ps[8 * 32 * 64]; // per-wave P [32 q][64 kv]

    const int bx = blockIdx.x;   // 0..7
    const int h  = blockIdx.y;
    const int b  = blockIdx.z;
    const size_t bh = (size_t)b * NH + h;
    const unsigned short* __restrict__ Qg = Qb  + bh * SEQ * HD;
    const unsigned short* __restrict__ Kg = Kb  + bh * SEQ * HD;
    const unsigned short* __restrict__ Vg = Vtb + bh * (size_t)HD * SEQ;

    const int tid = threadIdx.x;
    const int lane = tid & 63, w = tid >> 6;
    const int fr = lane & 15, fq = lane >> 4;

    const int qtB = 15 - bx;
    const int qt_eff = (w < 4) ? bx : qtB;
    const int qbase = qt_eff * 128 + (w & 3) * 32;
    const int qmaxw = qbase + 31;
    const int jstage = 2 * qtB + 1;          // qtB >= qtA always

    const int sr = tid >> 3, sc = tid & 7;
    const int lsw = sr * 64 + ((sc * 8) ^ ((sr & 7) << 3));

    short8 qa[2][2];
#pragma unroll
    for (int m = 0; m < 2; ++m)
#pragma unroll
        for (int ks = 0; ks < 2; ++ks)
            qa[m][ks] = *(const short8*)&Qg[(qbase + m * 16 + fr) * HD + ks * 32 + fq * 8];

    f32x4 o[2][4];
    float mold[2], lsum[2];
#pragma unroll
    for (int m = 0; m < 2; ++m) {
        mold[m] = -3e38f; lsum[m] = 0.f;
#pragma unroll
        for (int n = 0; n < 4; ++n) o[m][n] = (f32x4){0.f, 0.f, 0.f, 0.f};
    }

    short* const Pw = Ps + w * 2048;
    const int swz = (fr & 7) << 3;

    short8 kr = *(const short8*)&Kg[(size_t)sr * HD + sc * 8];
    short8 vr = *(const short8*)&Vg[(size_t)sr * SEQ + sc * 8];

    for (int j = 0; j <= jstage; ++j) {
        __syncthreads();
        *(short8*)&Ks[lsw] = kr;
        *(short8*)&Vs[lsw] = vr;
        __syncthreads();
        if (j < jstage) {
            kr = *(const short8*)&Kg[(size_t)((j + 1) * 64 + sr) * HD + sc * 8];
            vr = *(const short8*)&Vg[(size_t)sr * SEQ + (j + 1) * 64 + sc * 8];
        }
        if (j * 64 > qmaxw) continue;

        f32x4 st[4][2];
#pragma unroll
        for (int n = 0; n < 4; ++n)
#pragma unroll
            for (int m = 0; m < 2; ++m) st[n][m] = (f32x4){0.f, 0.f, 0.f, 0.f};
#pragma unroll
        for (int ks = 0; ks < 2; ++ks) {
            short8 kf[4];
#pragma unroll
            for (int n = 0; n < 4; ++n) {
                const int row = n * 16 + fr;
                kf[n] = *(const short8*)&Ks[row * 64 + ((ks * 32 + fq * 8) ^ ((row & 7) << 3))];
            }
            __builtin_amdgcn_s_setprio(1);
#pragma unroll
            for (int n = 0; n < 4; ++n)
#pragma unroll
                for (int m = 0; m < 2; ++m)
                    st[n][m] = __builtin_amdgcn_mfma_f32_16x16x32_bf16(
                        kf[n], qa[m][ks], st[n][m], 0, 0, 0);
            __builtin_amdgcn_s_setprio(0);
        }

        if (j * 64 + 63 > qbase) {
#pragma unroll
            for (int n = 0; n < 4; ++n) {
                const int kv = j * 64 + n * 16 + fq * 4;
#pragma unroll
                for (int m = 0; m < 2; ++m) {
                    const int q = qbase + m * 16 + fr;
#pragma unroll
                    for (int r = 0; r < 4; ++r)
                        if (kv + r > q) st[n][m][r] = -3e38f;
                }
            }
        }

        float pmax[2];
#pragma unroll
        for (int m = 0; m < 2; ++m) {
            float t0 = fmaxf(fmaxf(st[0][m][0], st[0][m][1]), fmaxf(st[0][m][2], st[0][m][3]));
            float t1 = fmaxf(fmaxf(st[1][m][0], st[1][m][1]), fmaxf(st[1][m][2], st[1][m][3]));
            float t2 = fmaxf(fmaxf(st[2][m][0], st[2][m][1]), fmaxf(st[2][m][2], st[2][m][3]));
            float t3 = fmaxf(fmaxf(st[3][m][0], st[3][m][1]), fmaxf(st[3][m][2], st[3][m][3]));
            float t = fmaxf(fmaxf(t0, t1), fmaxf(t2, t3));
            t = fmaxf(t, __shfl_xor(t, 16));
            t = fmaxf(t, __shfl_xor(t, 32));
            pmax[m] = t;
        }

        const float growth = fmaxf(pmax[0] - mold[0], pmax[1] - mold[1]);
        if (!__all(growth <= 8.0f)) {
            float resc[2];
#pragma unroll
            for (int m = 0; m < 2; ++m) {
                const float nm = fmaxf(mold[m], pmax[m]);
                resc[m] = exp2f(mold[m] - nm);
                mold[m] = nm;
                lsum[m] *= resc[m];
            }
#pragma unroll
            for (int m = 0; m < 2; ++m)
#pragma unroll
                for (int rr = 0; rr < 4; ++rr) {
                    const float rsc = __shfl(resc[m], fq * 4 + rr);
#pragma unroll
                    for (int n = 0; n < 4; ++n) o[m][n][rr] *= rsc;
                }
        }

#pragma unroll
        for (int m = 0; m < 2; ++m) {
            float rs = 0.f;
            const int prow = m * 16 + fr;
#pragma unroll
            for (int n = 0; n < 4; ++n) {
                const float p0 = exp2f(st[n][m][0] - mold[m]);
                const float p1 = exp2f(st[n][m][1] - mold[m]);
                const float p2 = exp2f(st[n][m][2] - mold[m]);
                const float p3 = exp2f(st[n][m][3] - mold[m]);
                rs += (p0 + p1) + (p2 + p3);
                ushort4 pk;
                pk.x = f2bf_fast(p0); pk.y = f2bf_fast(p1);
                pk.z = f2bf_fast(p2); pk.w = f2bf_fast(p3);
                *(ushort4*)&Pw[prow * 64 + ((n * 16 + fq * 4) ^ swz)] = pk;
            }
            rs += __shfl_xor(rs, 16);
            rs += __shfl_xor(rs, 32);
            lsum[m] += rs;
        }

#pragma unroll
        for (int ks = 0; ks < 2; ++ks) {
            short8 pa[2], vb[4];
#pragma unroll
            for (int m = 0; m < 2; ++m) {
                const int row = m * 16 + fr;
                pa[m] = *(const short8*)&Pw[row * 64 + ((ks * 32 + fq * 8) ^ swz)];
            }
#pragma unroll
            for (int n = 0; n < 4; ++n) {
                const int row = n * 16 + fr;
                vb[n] = *(const short8*)&Vs[row * 64 + ((ks * 32 + fq * 8) ^ ((row & 7) << 3))];
            }
            __builtin_amdgcn_s_setprio(1);
#pragma unroll
            for (int m = 0; m < 2; ++m)
#pragma unroll
                for (int n = 0; n < 4; ++n)
                    o[m][n] = __builtin_amdgcn_mfma_f32_16x16x32_bf16(
                        pa[m], vb[n], o[m][n], 0, 0, 0);
            __builtin_amdgcn_s_setprio(0);
        }
    }

#pragma unroll
    for (int m = 0; m < 2; ++m)
#pragma unroll
        for (int rr = 0; rr < 4; ++rr) {
            const float lv = __shfl(lsum[m], fq * 4 + rr);
            const float inv = 1.f / lv;
            const int q = qbase + m * 16 + fq * 4 + rr;
            const size_t rowoff = ((size_t)b * SEQ + q) * DEMB + h * HD;
#pragma unroll
            for (int n = 0; n < 4; ++n)
                ctx[rowoff + n * 16 + fr] = f2bf(o[m][n][rr] * inv);
        }
}

// ============================================================================
// O-projection, 2-phase double-buffered, both operands via global_load_lds
// (pre-swizzled source). ctx_bf16 @ Wob^T + bo -> out fp32.
// ============================================================================
__global__ __launch_bounds__(256) void gemm_out(
    const unsigned short* __restrict__ Cb, const unsigned short* __restrict__ Wob,
    const float* __restrict__ bo, float* __restrict__ Out)
{
    __shared__ __align__(16) short Asb[2][128 * 32];
    __shared__ __align__(16) short Bsb[2][128 * 32];

    const int tid = threadIdx.x;
    const int m0 = blockIdx.y * 128, n0 = blockIdx.x * 128;
    const int lane = tid & 63, w = tid >> 6;
    const int wr = w >> 1, wc = w & 1;
    const int fr = lane & 15, fq = lane >> 4;

    int soff[2];
#pragma unroll
    for (int i = 0; i < 2; ++i) {
        const int chunk = (w * 2 + i) * 64 + lane;
        const int row = chunk >> 2;
        const int cg = (chunk & 3) ^ ((row >> 1) & 3);
        soff[i] = row * 1024 + cg * 8;
    }
    const unsigned short* Abase = Cb + (size_t)m0 * 1024;
    const unsigned short* Bbase = Wob + (size_t)n0 * 1024;

    int offA[4], offB[4];
#pragma unroll
    for (int m = 0; m < 4; ++m) {
        const int rA = wr * 64 + m * 16 + fr;
        offA[m] = rA * 32 + ((fq ^ ((rA >> 1) & 3)) * 8);
        const int rB = wc * 64 + m * 16 + fr;
        offB[m] = rB * 32 + ((fq ^ ((rB >> 1) & 3)) * 8);
    }

    f32x4 acc[4][4];
#pragma unroll
    for (int m = 0; m < 4; ++m)
#pragma unroll
        for (int n = 0; n < 4; ++n) acc[m][n] = (f32x4){0.f, 0.f, 0.f, 0.f};

    // prologue: stage tile 0 into buffer 0
#pragma unroll
    for (int i = 0; i < 2; ++i) {
        gload_lds16(Abase + soff[i], &Asb[0][(w * 2 + i) * 512]);
        gload_lds16(Bbase + soff[i], &Bsb[0][(w * 2 + i) * 512]);
    }
    __syncthreads();

    int cur = 0;
    for (int t = 0; t < 32; ++t) {
        const int nxt = cur ^ 1;
        if (t < 31) {
            const int k1 = (t + 1) * 32;
#pragma unroll
            for (int i = 0; i < 2; ++i) {
                gload_lds16(Abase + soff[i] + k1, &Asb[nxt][(w * 2 + i) * 512]);
                gload_lds16(Bbase + soff[i] + k1, &Bsb[nxt][(w * 2 + i) * 512]);
            }
        }
        short8 af[4], bg[4];
#pragma unroll
        for (int m = 0; m < 4; ++m) af[m] = *(const short8*)&Asb[cur][offA[m]];
#pragma unroll
        for (int n = 0; n < 4; ++n) bg[n] = *(const short8*)&Bsb[cur][offB[n]];
#pragma unroll
        for (int m = 0; m < 4; ++m)
#pragma unroll
            for (int n = 0; n < 4; ++n)
                acc[m][n] = __builtin_amdgcn_mfma_f32_16x16x32_bf16(
                    af[m], bg[n], acc[m][n], 0, 0, 0);
        __syncthreads();
        cur = nxt;
    }

#pragma unroll
    for (int n = 0; n < 4; ++n) {
        const int col = n0 + wc * 64 + n * 16 + fr;
        const float bias = bo[col];
#pragma unroll
        for (int m = 0; m < 4; ++m) {
            const int rowb = m0 + wr * 64 + m * 16 + fq * 4;
#pragma unroll
            for (int r = 0; r < 4; ++r)
                Out[(size_t)(rowb + r) * DEMB + col] = acc[m][n][r] + bias;
        }
    }
}

extern "C" void kernel_launch(void* const* d_in, const int* in_sizes, int n_in,
                              void* d_out, int out_size, void* d_ws, size_t ws_size,
                              hipStream_t stream) {
    const float* x  = (const float*)d_in[0];
    const float* Wq = (const float*)d_in[1];
    const float* Wk = (const float*)d_in[2];
    const float* Wv = (const float*)d_in[3];
    const float* Wo = (const float*)d_in[4];
    const float* bo = (const float*)d_in[5];
    float* out = (float*)d_out;

    char* w = (char*)d_ws;
    const size_t MB = 1024 * 1024;
    unsigned short* Qb   = (unsigned short*)(w);            //  8 MB
    unsigned short* Kb   = (unsigned short*)(w + 8  * MB);  //  8 MB
    unsigned short* Vb   = (unsigned short*)(w + 16 * MB);  //  8 MB [b,h,s,d]
    unsigned short* Cb   = (unsigned short*)(w + 24 * MB);  //  8 MB ctx
    unsigned short* Vtb  = (unsigned short*)(w + 32 * MB);  //  8 MB [b,h,d,s]
    unsigned short* Wb   = (unsigned short*)(w + 40 * MB);  //  6 MB (q|k|v)
    unsigned short* Wob  = (unsigned short*)(w + 46 * MB);  //  2 MB

    cast_w<<<4096, 256, 0, stream>>>(Wq, Wk, Wv, Wo, Wb, Wob);
    gemm_qkv<<<dim3(24, 32), 256, 0, stream>>>(x, Wb, Qb, Kb, Vb);
    transpose_v<<<dim3(SEQ / 64, NBATCH * NH), 256, 0, stream>>>(Vb, Vtb);
    flash_mfma2<<<dim3(8, NH, NBATCH), 512, 0, stream>>>(Qb, Kb, Vtb, Cb);
    gemm_out<<<dim3(8, 32), 256, 0, stream>>>(Cb, Wob, bo, out);
}

// Round 9
// 200.647 us; speedup vs baseline: 1.1307x; 1.0726x over previous
//
#include <hip/hip_runtime.h>
#include <math.h>

#define SEQ 2048
#define NBATCH 2
#define DEMB 1024
#define NH 16
#define HD 64
#define NROWS (NBATCH * SEQ) // 4096

typedef __attribute__((ext_vector_type(8))) short short8;   // 8 bf16 (4 VGPR)
typedef __attribute__((ext_vector_type(4))) float f32x4;    // MFMA acc

__device__ __forceinline__ unsigned short f2bf(float f) {
    unsigned int u = __float_as_uint(f);
    u = (u + 0x7FFFu + ((u >> 16) & 1u)) >> 16;   // RNE
    return (unsigned short)u;
}
__device__ __forceinline__ unsigned short f2bf_fast(float f) {
    return (unsigned short)((__float_as_uint(f) + 0x8000u) >> 16); // round-half-up
}

// ============================================================================
// Cast fp32 inputs to bf16 (R2-proven). Wq pre-scaled by 0.125*log2(e) so
// attention softmax runs in the exp2 domain.
// ============================================================================
__global__ __launch_bounds__(256) void cast_bf16(
    const float* __restrict__ x, const float* __restrict__ wq,
    const float* __restrict__ wk, const float* __restrict__ wv,
    const float* __restrict__ wo,
    unsigned short* __restrict__ Xb, unsigned short* __restrict__ Wb,
    unsigned short* __restrict__ Wob)
{
    const int q = blockIdx.x * 256 + threadIdx.x; // quad index
    float4 v; unsigned short* dst; float sc = 1.f;
    if (q < 1048576) {                       // X: 4194304 elems
        v = ((const float4*)x)[q];
        dst = Xb + q * 4;
    } else if (q < 1835008) {                // Wq|Wk|Wv concat: 3145728 elems
        const int e = (q - 1048576) * 4;
        const int which = e >> 20;
        const int off = e & 1048575;
        const float* s = (which == 0) ? wq : (which == 1) ? wk : wv;
        v = *(const float4*)&s[off];
        sc = (which == 0) ? 0.18033688011112042f : 1.f;  // 0.125*log2(e)
        dst = Wb + e;
    } else {                                 // Wo: 1048576 elems
        const int j = q - 1835008;
        v = ((const float4*)wo)[j];
        dst = Wob + j * 4;
    }
    ushort4 o;
    o.x = f2bf(v.x * sc); o.y = f2bf(v.y * sc);
    o.z = f2bf(v.z * sc); o.w = f2bf(v.w * sc);
    *(ushort4*)dst = o;
}

// ============================================================================
// QKV GEMM (R2-proven reg-staged structure) + FUSED V-transpose epilogue.
// A=Xb[4096][1024], B=Wb[3072][1024]. 128x128 tile, BK=32, 4 waves.
// Q,K written bf16 [b,h,s,d] (scalar stores); V written TRANSPOSED
// [b,h,d,s] via a 16KB LDS staging transpose (2 passes of 64 d-rows):
//   T[d][s ^ ((d&7)<<3)] — scalar writes <=2-way conflicts, b128 reads clean,
//   global Vt stores coalesce as 16-lane x 16B = 256B runs.
// ============================================================================
__global__ __launch_bounds__(256) void gemm_qkv(
    const unsigned short* __restrict__ Xb, const unsigned short* __restrict__ Wb,
    unsigned short* __restrict__ Qb, unsigned short* __restrict__ Kb,
    unsigned short* __restrict__ Vtb)
{
    __shared__ __align__(16) short SM[8192];   // As = SM[0..4095], Bs = SM[4096..]
    short* const As = SM;
    short* const Bs = SM + 4096;

    const int tid = threadIdx.x;
    const int nblk = blockIdx.x;              // 0..23
    const int which = nblk >> 3;              // 0=Q 1=K 2=V
    const int n0c = (nblk & 7) * 128;         // col offset within one matrix
    const int m0 = blockIdx.y * 128;

    const int sr = tid >> 2, sg = tid & 3;
    const int slot = sg ^ ((sr >> 1) & 3);    // 2-way-free XOR swizzle
    const int st0 = sr * 32 + slot * 8;
    const int st1 = (sr + 64) * 32 + slot * 8;

    const int lane = tid & 63, w = tid >> 6;
    const int wr = w >> 1, wc = w & 1;
    const int fr = lane & 15, fq = lane >> 4;

    int offA[4], offB[4];
#pragma unroll
    for (int m = 0; m < 4; ++m) {
        const int rA = wr * 64 + m * 16 + fr;
        offA[m] = rA * 32 + ((fq ^ ((rA >> 1) & 3)) * 8);
        const int rB = wc * 64 + m * 16 + fr;
        offB[m] = rB * 32 + ((fq ^ ((rB >> 1) & 3)) * 8);
    }

    f32x4 acc[4][4];
#pragma unroll
    for (int m = 0; m < 4; ++m)
#pragma unroll
        for (int n = 0; n < 4; ++n) acc[m][n] = (f32x4){0.f, 0.f, 0.f, 0.f};

    const unsigned short* Wmat = Wb + (size_t)which * 1024 * 1024;
    const unsigned short* ga0 = Xb + (m0 + sr) * 1024 + sg * 8;
    const unsigned short* ga1 = Xb + (m0 + 64 + sr) * 1024 + sg * 8;
    const unsigned short* gb0 = Wmat + (n0c + sr) * 1024 + sg * 8;
    const unsigned short* gb1 = Wmat + (n0c + 64 + sr) * 1024 + sg * 8;

    short8 ra0 = *(const short8*)ga0, ra1 = *(const short8*)ga1;
    short8 rb0 = *(const short8*)gb0, rb1 = *(const short8*)gb1;

    for (int k = 0; k < 32; ++k) {
        __syncthreads();
        *(short8*)&As[st0] = ra0; *(short8*)&As[st1] = ra1;
        *(short8*)&Bs[st0] = rb0; *(short8*)&Bs[st1] = rb1;
        __syncthreads();
        if (k < 31) {
            ga0 += 32; ga1 += 32; gb0 += 32; gb1 += 32;
            ra0 = *(const short8*)ga0; ra1 = *(const short8*)ga1;
            rb0 = *(const short8*)gb0; rb1 = *(const short8*)gb1;
        }
        short8 af[4], bg[4];
#pragma unroll
        for (int m = 0; m < 4; ++m) af[m] = *(const short8*)&As[offA[m]];
#pragma unroll
        for (int n = 0; n < 4; ++n) bg[n] = *(const short8*)&Bs[offB[n]];
#pragma unroll
        for (int m = 0; m < 4; ++m)
#pragma unroll
            for (int n = 0; n < 4; ++n)
                acc[m][n] = __builtin_amdgcn_mfma_f32_16x16x32_bf16(
                    af[m], bg[n], acc[m][n], 0, 0, 0);
    }

    const int b_ = m0 >> 11;          // batch
    const int s_base = m0 & 2047;     // seq offset within batch

    if (which < 2) {
        // ---- Q/K epilogue: scalar stores to [b,h,s,d] ----
        unsigned short* Out = (which == 0) ? Qb : Kb;
#pragma unroll
        for (int n = 0; n < 4; ++n) {
            const int col = n0c + wc * 64 + n * 16 + fr;
            const int h = col >> 6;
            const int d = col & 63;
#pragma unroll
            for (int m = 0; m < 4; ++m) {
                const int srow = s_base + wr * 64 + m * 16 + fq * 4;
#pragma unroll
                for (int r = 0; r < 4; ++r)
                    Out[(((size_t)b_ * NH + h) * SEQ + srow + r) * HD + (col & 63)] =
                        f2bf(acc[m][n][r]);
            }
        }
    } else {
        // ---- V epilogue: LDS transpose, write Vt [b,h,d,s] coalesced ----
        const int h0 = (n0c >> 6);    // first head of this tile (2 heads)
#pragma unroll
        for (int p = 0; p < 2; ++p) {
            __syncthreads();          // LDS free (K-loop reads / prev pass done)
            if (wc == p) {
#pragma unroll
                for (int n = 0; n < 4; ++n) {
                    const int dl = n * 16 + fr;           // 0..63 within pass
                    const int sw = (dl & 7) << 3;
#pragma unroll
                    for (int m = 0; m < 4; ++m) {
#pragma unroll
                        for (int r = 0; r < 4; ++r) {
                            const int s = wr * 64 + m * 16 + fq * 4 + r;
                            SM[dl * 128 + (s ^ sw)] = f2bf(acc[m][n][r]);
                        }
                    }
                }
            }
            __syncthreads();
            // read-out: wave w owns d-rows w*16..w*16+15; 16 lanes cover s
            unsigned short* dstbase =
                Vtb + (((size_t)b_ * NH + h0 + p) * HD) * SEQ;
#pragma unroll
            for (int i = 0; i < 4; ++i) {
                const int dl = w * 16 + i * 4 + fq;
                const short8 v = *(const short8*)&SM[dl * 128 + ((fr * 8) ^ ((dl & 7) << 3))];
                *(short8*)&dstbase[(size_t)dl * SEQ + s_base + fr * 8] = v;
            }
        }
    }
}

// ============================================================================
// MFMA flash attention (R8-proven, 58.8-64.4 us).
// 256 blocks x 512 threads. Waves 0-3: qt=bx; waves 4-7: qt=15-bx.
// Shared K/Vt LDS staging (XOR-swizzled); swapped QK^T softmax; defer-max.
// ============================================================================
__global__ __launch_bounds__(512) void flash_mfma2(
    const unsigned short* __restrict__ Qb, const unsigned short* __restrict__ Kb,
    const unsigned short* __restrict__ Vtb, unsigned short* __restrict__ ctx)
{
    __shared__ __align__(16) short Ks[64 * 64];
    __shared__ __align__(16) short Vs[64 * 64];     // Vt tile [d][kv]
    __shared__ __align__(16) short Ps[8 * 32 * 64]; // per-wave P [32 q][64 kv]

    const int bx = blockIdx.x;   // 0..7
    const int h  = blockIdx.y;
    const int b  = blockIdx.z;
    const size_t bh = (size_t)b * NH + h;
    const unsigned short* __restrict__ Qg = Qb  + bh * SEQ * HD;
    const unsigned short* __restrict__ Kg = Kb  + bh * SEQ * HD;
    const unsigned short* __restrict__ Vg = Vtb + bh * (size_t)HD * SEQ;

    const int tid = threadIdx.x;
    const int lane = tid & 63, w = tid >> 6;
    const int fr = lane & 15, fq = lane >> 4;

    const int qtB = 15 - bx;
    const int qt_eff = (w < 4) ? bx : qtB;
    const int qbase = qt_eff * 128 + (w & 3) * 32;
    const int qmaxw = qbase + 31;
    const int jstage = 2 * qtB + 1;          // qtB >= qtA always

    const int sr = tid >> 3, sc = tid & 7;
    const int lsw = sr * 64 + ((sc * 8) ^ ((sr & 7) << 3));

    short8 qa[2][2];
#pragma unroll
    for (int m = 0; m < 2; ++m)
#pragma unroll
        for (int ks = 0; ks < 2; ++ks)
            qa[m][ks] = *(const short8*)&Qg[(qbase + m * 16 + fr) * HD + ks * 32 + fq * 8];

    f32x4 o[2][4];
    float mold[2], lsum[2];
#pragma unroll
    for (int m = 0; m < 2; ++m) {
        mold[m] = -3e38f; lsum[m] = 0.f;
#pragma unroll
        for (int n = 0; n < 4; ++n) o[m][n] = (f32x4){0.f, 0.f, 0.f, 0.f};
    }

    short* const Pw = Ps + w * 2048;
    const int swz = (fr & 7) << 3;

    short8 kr = *(const short8*)&Kg[(size_t)sr * HD + sc * 8];
    short8 vr = *(const short8*)&Vg[(size_t)sr * SEQ + sc * 8];

    for (int j = 0; j <= jstage; ++j) {
        __syncthreads();
        *(short8*)&Ks[lsw] = kr;
        *(short8*)&Vs[lsw] = vr;
        __syncthreads();
        if (j < jstage) {
            kr = *(const short8*)&Kg[(size_t)((j + 1) * 64 + sr) * HD + sc * 8];
            vr = *(const short8*)&Vg[(size_t)sr * SEQ + (j + 1) * 64 + sc * 8];
        }
        if (j * 64 > qmaxw) continue;

        f32x4 st[4][2];
#pragma unroll
        for (int n = 0; n < 4; ++n)
#pragma unroll
            for (int m = 0; m < 2; ++m) st[n][m] = (f32x4){0.f, 0.f, 0.f, 0.f};
#pragma unroll
        for (int ks = 0; ks < 2; ++ks) {
            short8 kf[4];
#pragma unroll
            for (int n = 0; n < 4; ++n) {
                const int row = n * 16 + fr;
                kf[n] = *(const short8*)&Ks[row * 64 + ((ks * 32 + fq * 8) ^ ((row & 7) << 3))];
            }
            __builtin_amdgcn_s_setprio(1);
#pragma unroll
            for (int n = 0; n < 4; ++n)
#pragma unroll
                for (int m = 0; m < 2; ++m)
                    st[n][m] = __builtin_amdgcn_mfma_f32_16x16x32_bf16(
                        kf[n], qa[m][ks], st[n][m], 0, 0, 0);
            __builtin_amdgcn_s_setprio(0);
        }

        if (j * 64 + 63 > qbase) {
#pragma unroll
            for (int n = 0; n < 4; ++n) {
                const int kv = j * 64 + n * 16 + fq * 4;
#pragma unroll
                for (int m = 0; m < 2; ++m) {
                    const int q = qbase + m * 16 + fr;
#pragma unroll
                    for (int r = 0; r < 4; ++r)
                        if (kv + r > q) st[n][m][r] = -3e38f;
                }
            }
        }

        float pmax[2];
#pragma unroll
        for (int m = 0; m < 2; ++m) {
            float t0 = fmaxf(fmaxf(st[0][m][0], st[0][m][1]), fmaxf(st[0][m][2], st[0][m][3]));
            float t1 = fmaxf(fmaxf(st[1][m][0], st[1][m][1]), fmaxf(st[1][m][2], st[1][m][3]));
            float t2 = fmaxf(fmaxf(st[2][m][0], st[2][m][1]), fmaxf(st[2][m][2], st[2][m][3]));
            float t3 = fmaxf(fmaxf(st[3][m][0], st[3][m][1]), fmaxf(st[3][m][2], st[3][m][3]));
            float t = fmaxf(fmaxf(t0, t1), fmaxf(t2, t3));
            t = fmaxf(t, __shfl_xor(t, 16));
            t = fmaxf(t, __shfl_xor(t, 32));
            pmax[m] = t;
        }

        const float growth = fmaxf(pmax[0] - mold[0], pmax[1] - mold[1]);
        if (!__all(growth <= 8.0f)) {
            float resc[2];
#pragma unroll
            for (int m = 0; m < 2; ++m) {
                const float nm = fmaxf(mold[m], pmax[m]);
                resc[m] = exp2f(mold[m] - nm);
                mold[m] = nm;
                lsum[m] *= resc[m];
            }
#pragma unroll
            for (int m = 0; m < 2; ++m)
#pragma unroll
                for (int rr = 0; rr < 4; ++rr) {
                    const float rsc = __shfl(resc[m], fq * 4 + rr);
#pragma unroll
                    for (int n = 0; n < 4; ++n) o[m][n][rr] *= rsc;
                }
        }

#pragma unroll
        for (int m = 0; m < 2; ++m) {
            float rs = 0.f;
            const int prow = m * 16 + fr;
#pragma unroll
            for (int n = 0; n < 4; ++n) {
                const float p0 = exp2f(st[n][m][0] - mold[m]);
                const float p1 = exp2f(st[n][m][1] - mold[m]);
                const float p2 = exp2f(st[n][m][2] - mold[m]);
                const float p3 = exp2f(st[n][m][3] - mold[m]);
                rs += (p0 + p1) + (p2 + p3);
                ushort4 pk;
                pk.x = f2bf_fast(p0); pk.y = f2bf_fast(p1);
                pk.z = f2bf_fast(p2); pk.w = f2bf_fast(p3);
                *(ushort4*)&Pw[prow * 64 + ((n * 16 + fq * 4) ^ swz)] = pk;
            }
            rs += __shfl_xor(rs, 16);
            rs += __shfl_xor(rs, 32);
            lsum[m] += rs;
        }

#pragma unroll
        for (int ks = 0; ks < 2; ++ks) {
            short8 pa[2], vb[4];
#pragma unroll
            for (int m = 0; m < 2; ++m) {
                const int row = m * 16 + fr;
                pa[m] = *(const short8*)&Pw[row * 64 + ((ks * 32 + fq * 8) ^ swz)];
            }
#pragma unroll
            for (int n = 0; n < 4; ++n) {
                const int row = n * 16 + fr;
                vb[n] = *(const short8*)&Vs[row * 64 + ((ks * 32 + fq * 8) ^ ((row & 7) << 3))];
            }
            __builtin_amdgcn_s_setprio(1);
#pragma unroll
            for (int m = 0; m < 2; ++m)
#pragma unroll
                for (int n = 0; n < 4; ++n)
                    o[m][n] = __builtin_amdgcn_mfma_f32_16x16x32_bf16(
                        pa[m], vb[n], o[m][n], 0, 0, 0);
            __builtin_amdgcn_s_setprio(0);
        }
    }

#pragma unroll
    for (int m = 0; m < 2; ++m)
#pragma unroll
        for (int rr = 0; rr < 4; ++rr) {
            const float lv = __shfl(lsum[m], fq * 4 + rr);
            const float inv = 1.f / lv;
            const int q = qbase + m * 16 + fq * 4 + rr;
            const size_t rowoff = ((size_t)b * SEQ + q) * DEMB + h * HD;
#pragma unroll
            for (int n = 0; n < 4; ++n)
                ctx[rowoff + n * 16 + fr] = f2bf(o[m][n][rr] * inv);
        }
}

// ============================================================================
// O-projection (R2-proven reg-staged): ctx_bf16 @ Wob^T + bo -> out fp32.
// ============================================================================
__global__ __launch_bounds__(256) void gemm_out(
    const unsigned short* __restrict__ Cb, const unsigned short* __restrict__ Wob,
    const float* __restrict__ bo, float* __restrict__ Out)
{
    __shared__ __align__(16) short As[128 * 32];
    __shared__ __align__(16) short Bs[128 * 32];

    const int tid = threadIdx.x;
    const int m0 = blockIdx.y * 128, n0 = blockIdx.x * 128;
    const int sr = tid >> 2, sg = tid & 3;
    const int slot = sg ^ ((sr >> 1) & 3);
    const int st0 = sr * 32 + slot * 8;
    const int st1 = (sr + 64) * 32 + slot * 8;

    const int lane = tid & 63, w = tid >> 6;
    const int wr = w >> 1, wc = w & 1;
    const int fr = lane & 15, fq = lane >> 4;

    int offA[4], offB[4];
#pragma unroll
    for (int m = 0; m < 4; ++m) {
        const int rA = wr * 64 + m * 16 + fr;
        offA[m] = rA * 32 + ((fq ^ ((rA >> 1) & 3)) * 8);
        const int rB = wc * 64 + m * 16 + fr;
        offB[m] = rB * 32 + ((fq ^ ((rB >> 1) & 3)) * 8);
    }

    f32x4 acc[4][4];
#pragma unroll
    for (int m = 0; m < 4; ++m)
#pragma unroll
        for (int n = 0; n < 4; ++n) acc[m][n] = (f32x4){0.f, 0.f, 0.f, 0.f};

    const unsigned short* ga0 = Cb + (m0 + sr) * 1024 + sg * 8;
    const unsigned short* ga1 = Cb + (m0 + 64 + sr) * 1024 + sg * 8;
    const unsigned short* gb0 = Wob + (n0 + sr) * 1024 + sg * 8;
    const unsigned short* gb1 = Wob + (n0 + 64 + sr) * 1024 + sg * 8;

    short8 ra0 = *(const short8*)ga0, ra1 = *(const short8*)ga1;
    short8 rb0 = *(const short8*)gb0, rb1 = *(const short8*)gb1;

    for (int k = 0; k < 32; ++k) {
        __syncthreads();
        *(short8*)&As[st0] = ra0; *(short8*)&As[st1] = ra1;
        *(short8*)&Bs[st0] = rb0; *(short8*)&Bs[st1] = rb1;
        __syncthreads();
        if (k < 31) {
            ga0 += 32; ga1 += 32; gb0 += 32; gb1 += 32;
            ra0 = *(const short8*)ga0; ra1 = *(const short8*)ga1;
            rb0 = *(const short8*)gb0; rb1 = *(const short8*)gb1;
        }
        short8 af[4], bg[4];
#pragma unroll
        for (int m = 0; m < 4; ++m) af[m] = *(const short8*)&As[offA[m]];
#pragma unroll
        for (int n = 0; n < 4; ++n) bg[n] = *(const short8*)&Bs[offB[n]];
#pragma unroll
        for (int m = 0; m < 4; ++m)
#pragma unroll
            for (int n = 0; n < 4; ++n)
                acc[m][n] = __builtin_amdgcn_mfma_f32_16x16x32_bf16(
                    af[m], bg[n], acc[m][n], 0, 0, 0);
    }

#pragma unroll
    for (int n = 0; n < 4; ++n) {
        const int col = n0 + wc * 64 + n * 16 + fr;
        const float bias = bo[col];
#pragma unroll
        for (int m = 0; m < 4; ++m) {
            const int rowb = m0 + wr * 64 + m * 16 + fq * 4;
#pragma unroll
            for (int r = 0; r < 4; ++r)
                Out[(size_t)(rowb + r) * DEMB + col] = acc[m][n][r] + bias;
        }
    }
}

extern "C" void kernel_launch(void* const* d_in, const int* in_sizes, int n_in,
                              void* d_out, int out_size, void* d_ws, size_t ws_size,
                              hipStream_t stream) {
    const float* x  = (const float*)d_in[0];
    const float* Wq = (const float*)d_in[1];
    const float* Wk = (const float*)d_in[2];
    const float* Wv = (const float*)d_in[3];
    const float* Wo = (const float*)d_in[4];
    const float* bo = (const float*)d_in[5];
    float* out = (float*)d_out;

    char* w = (char*)d_ws;
    const size_t MB = 1024 * 1024;
    unsigned short* Qb   = (unsigned short*)(w);            //  8 MB
    unsigned short* Kb   = (unsigned short*)(w + 8  * MB);  //  8 MB
    unsigned short* Vtb  = (unsigned short*)(w + 16 * MB);  //  8 MB [b,h,d,s]
    unsigned short* Cb   = (unsigned short*)(w + 24 * MB);  //  8 MB ctx
    unsigned short* Xb   = (unsigned short*)(w + 32 * MB);  //  8 MB
    unsigned short* Wb   = (unsigned short*)(w + 40 * MB);  //  6 MB (q|k|v)
    unsigned short* Wob  = (unsigned short*)(w + 46 * MB);  //  2 MB

    cast_bf16<<<8192, 256, 0, stream>>>(x, Wq, Wk, Wv, Wo, Xb, Wb, Wob);
    gemm_qkv<<<dim3(24, 32), 256, 0, stream>>>(Xb, Wb, Qb, Kb, Vtb);
    flash_mfma2<<<dim3(8, NH, NBATCH), 512, 0, stream>>>(Qb, Kb, Vtb, Cb);
    gemm_out<<<dim3(8, 32), 256, 0, stream>>>(Cb, Wob, bo, out);
}